// Round 3
// baseline (256.204 us; speedup 1.0000x reference)
//
#include <hip/hip_runtime.h>
#include <cmath>

#define BATCH 32768

struct cplx { float x, y; };
__device__ __forceinline__ cplx cadd(cplx a, cplx b){ return {a.x+b.x, a.y+b.y}; }
__device__ __forceinline__ cplx csub(cplx a, cplx b){ return {a.x-b.x, a.y-b.y}; }
__device__ __forceinline__ cplx cmul(cplx a, cplx b){ return {a.x*b.x - a.y*b.y, a.x*b.y + a.y*b.x}; }
__device__ __forceinline__ cplx cmul_mi(cplx a){ return {a.y, -a.x}; }                 // a * (-i)
__device__ __forceinline__ cplx cmul_w81(cplx a){ const float c=0.70710678f; return {c*(a.x+a.y), c*(a.y-a.x)}; } // a*W8^1
__device__ __forceinline__ cplx cmul_w83(cplx a){ const float c=0.70710678f; return {c*(a.y-a.x), -c*(a.x+a.y)}; } // a*W8^3

// 8-point DFT, natural-order in/out: A_r = sum_m a_m * W8^{r m}
__device__ __forceinline__ void dft8(cplx a[8]) {
    cplx t0=cadd(a[0],a[4]), t4=csub(a[0],a[4]);
    cplx t1=cadd(a[1],a[5]), t5=csub(a[1],a[5]);
    cplx t2=cadd(a[2],a[6]), t6=csub(a[2],a[6]);
    cplx t3=cadd(a[3],a[7]), t7=csub(a[3],a[7]);
    cplx u0=cadd(t0,t2), u2=csub(t0,t2);
    cplx u1=cadd(t1,t3), u3=cmul_mi(csub(t1,t3));
    a[0]=cadd(u0,u1); a[4]=csub(u0,u1); a[2]=cadd(u2,u3); a[6]=csub(u2,u3);
    cplx v0=t4, v1=cmul_w81(t5), v2=cmul_mi(t6), v3=cmul_w83(t7);
    cplx w0=cadd(v0,v2), w2=csub(v0,v2);
    cplx w1=cadd(v1,v3), w3=cmul_mi(csub(v1,v3));
    a[1]=cadd(w0,w1); a[5]=csub(w0,w1); a[3]=cadd(w2,w3); a[7]=csub(w2,w3);
}

// Replicates JAX fp32 argmin(|freq - target|), first-occurrence tie-break.
__device__ __forceinline__ int nearest_bin(float fs, float target) {
    float x = target * 1024.0f / fs;
    int i0 = (int)floorf(x);
    int lo = max(0, i0 - 1), hi = min(512, i0 + 2);
    int bi = lo; float bd = 1e30f;
    for (int i = lo; i <= hi; ++i) {
        float fr = (fs * 0.5f) * ((float)i / 512.0f);
        float d = fabsf(fr - target);
        if (d < bd) { bd = d; bi = i; }
    }
    return bi;
}

// One wave (64 lanes) per row. 512-pt complex FFT of packed even/odd samples
// (radix 8x8x8, register DFT-8s, intra-wave LDS transposes), then rfft combine
// done entirely in registers via __shfl (conjugate partner = fixed lane perm).
//
// Epilogue (round-3): each block adds blocksum/BATCH to out[0] with a plain
// RELAXED device-scope atomicAdd (no acq/rel!). Round-1 post-mortem: ACQ_REL
// RMWs emit buffer_wbl2/buffer_inv per-XCD L2 maintenance -> 8192 of them cost
// ~440 us. Relaxed atomicAdd executes at the coherent point with no cache
// maintenance (m20) and is amortized over the kernel lifetime. out[0] is
// zeroed by a 4-byte hipMemsetAsync in kernel_launch (d_out is poisoned).
__global__ __launch_bounds__(256) void fft_loss_kernel(
    const float* __restrict__ preds, const float* __restrict__ Fs,
    float* __restrict__ out)
{
    __shared__ float sre[4][576];   // per-wave: 8 rows x stride 72 (conflict-free)
    __shared__ float sim[4][576];
    __shared__ float sblk[4];

    const int tid  = threadIdx.x;
    const int wv   = tid >> 6;
    const int lane = tid & 63;
    const int row  = blockIdx.x * 4 + wv;

    float* re = sre[wv];
    float* im = sim[wv];

    const float fs = Fs[row];       // wave-uniform: s_load, issued early

    // z[n] = x[2n] + i*x[2n+1] == float2 view of the row.
    const float2* x2 = reinterpret_cast<const float2*>(preds) + (size_t)row * 512;

    // ---- Stage A: lane = n0; DFT8 over n1 (stride-64 elements) ----
    cplx z[8];
#pragma unroll
    for (int n1 = 0; n1 < 8; ++n1) {
        float2 v = x2[n1 * 64 + lane];
        z[n1] = {v.x, v.y};
    }
    dft8(z);
    {   // twiddle W_512^{r*n0}, depth-3 power tree (verified: absmax 0.0)
        float sb, cb;
        __sincosf(-0.012271846f * (float)lane, &sb, &cb);   // -2pi/512 * lane
        cplx w1 = {cb, sb};
        cplx w2 = cmul(w1, w1);
        cplx w3 = cmul(w2, w1);
        cplx w4 = cmul(w2, w2);
        cplx w5 = cmul(w4, w1);
        cplx w6 = cmul(w4, w2);
        cplx w7 = cmul(w4, w3);
        z[1]=cmul(z[1],w1); z[2]=cmul(z[2],w2); z[3]=cmul(z[3],w3); z[4]=cmul(z[4],w4);
        z[5]=cmul(z[5],w5); z[6]=cmul(z[6],w6); z[7]=cmul(z[7],w7);
    }
#pragma unroll
    for (int r = 0; r < 8; ++r) { re[r*72 + lane] = z[r].x; im[r*72 + lane] = z[r].y; }

    // ---- Stage B: lane = (r, m0); DFT8 over m1 ----
    const int rB = lane & 7, m0 = lane >> 3;
    cplx b[8];
#pragma unroll
    for (int m1 = 0; m1 < 8; ++m1) {
        int a = rB*72 + 8*m1 + m0;
        b[m1] = {re[a], im[a]};
    }
    dft8(b);
    {   // twiddle W_64^{s*m0}, depth-3 power tree
        float sb, cb;
        __sincosf(-0.09817477f * (float)m0, &sb, &cb);      // -2pi/64 * m0
        cplx w1 = {cb, sb};
        cplx w2 = cmul(w1, w1);
        cplx w3 = cmul(w2, w1);
        cplx w4 = cmul(w2, w2);
        cplx w5 = cmul(w4, w1);
        cplx w6 = cmul(w4, w2);
        cplx w7 = cmul(w4, w3);
        b[1]=cmul(b[1],w1); b[2]=cmul(b[2],w2); b[3]=cmul(b[3],w3); b[4]=cmul(b[4],w4);
        b[5]=cmul(b[5],w5); b[6]=cmul(b[6],w6); b[7]=cmul(b[7],w7);
    }
#pragma unroll
    for (int s = 0; s < 8; ++s) {   // XOR-swizzled 8x8 transpose (2-way banks both sides)
        int a = rB*72 + 8*m0 + ((s + m0) & 7);
        re[a] = b[s].x; im[a] = b[s].y;
    }

    // ---- Stage C: lane = (r, s); DFT8 over m0 -> Z[lane + 64 t] = c[t] (registers) ----
    const int sC = lane >> 3;
    cplx c[8];
#pragma unroll
    for (int m = 0; m < 8; ++m) {
        int a = rB*72 + 8*m + ((sC + m) & 7);
        c[m] = {re[a], im[a]};
    }
    dft8(c);
    // Z stays in registers: conjugate partner Z[(512-k)&511] for k=lane+64t is
    // c[7-t] at lane (64-lane)&63  (lane 0: local c[(8-t)&7]).

    // ---- rfft combine: X[k] = E + W_1024^k * O, psd = |X|^2 ----
    const int left  = nearest_bin(fs, (float)(40.0/60.0));
    const int right = nearest_bin(fs, 3.0f);

    float total = 0.f, inb = 0.f, best = -1.f;
    int besti = 1 << 30;
    float sk, ck;
    __sincosf(-0.0061359233f * (float)lane, &sk, &ck);      // -2pi/1024 * lane
    const cplx wb = {ck, sk};
    // W_16^t = W_1024^{64 t}: compile-time constants -> independent cmuls (no chain)
    const float c16r[8] = { 1.f,  0.92387953f,  0.70710678f,  0.38268343f,
                            0.f, -0.38268343f, -0.70710678f, -0.92387953f };
    const float c16i[8] = { 0.f, -0.38268343f, -0.70710678f, -0.92387953f,
                           -1.f, -0.92387953f, -0.70710678f, -0.38268343f };
    const int srcl = (64 - lane) & 63;
    const bool l0 = (lane == 0);
#pragma unroll
    for (int t = 0; t < 8; ++t) {
        int k  = lane + 64*t;
        cplx a = c[t];
        // partner via lane shuffle (t indices are unroll-constants: no scratch)
        float pxr = __shfl(c[7-t].x, srcl);
        float pxi = __shfl(c[7-t].y, srcl);
        float bx = l0 ? c[(8-t)&7].x : pxr;
        float by = l0 ? c[(8-t)&7].y : pxi;
        // bb = conj(Z[k2])
        float ex = 0.5f*(a.x + bx), ey = 0.5f*(a.y - by);
        float dx = a.x - bx,        dy = a.y + by;
        float ox = 0.5f*dy,          oy = -0.5f*dx;
        cplx wk = cmul(wb, {c16r[t], c16i[t]});
        float Xr = ex + wk.x*ox - wk.y*oy;
        float Xi = ey + wk.x*oy + wk.y*ox;
        float v  = Xr*Xr + Xi*Xi;
        re[k] = v;                  // psd store (same-wave LDS ops are in-order:
                                    // all stage-C reads already issued)
        total += v;
        if (k >= left && k < right) {
            inb += v;
            if (v > best) { best = v; besti = k; }
        }
    }
    if (lane == 0) {                // Nyquist bin k=512 (never in band)
        float d = c[0].x - c[0].y;
        float p512 = d*d;
        total += p512;
        re[512] = p512;
    }

    // ---- wave reduce: sums + argmax (min-index tie-break) ----
#pragma unroll
    for (int off = 32; off > 0; off >>= 1) {
        total += __shfl_down(total, off);
        inb   += __shfl_down(inb, off);
        float ob = __shfl_down(best, off);
        int   oi = __shfl_down(besti, off);
        if (ob > best || (ob == best && oi < besti)) { best = ob; besti = oi; }
    }
    if (lane == 0) {
        int delta = (int)rintf(0.1f / ((fs * 0.5f) / 513.0f));
        if (delta < 1) delta = 1;                       // delta in {3,4} for fs in [25,35)
        int lo = max(left, besti - delta), hi = min(right, besti + delta);
        float wsum = 0.f;
        for (int f = lo; f < hi; ++f) wsum += re[f];
        float band = (total - inb) / (1e-8f + total);
        float den  = inb + 1e-8f * (float)(right - left);
        sblk[wv] = band + (inb - wsum) / den;
    }
    __syncthreads();
    if (tid == 0) {
        float bs = (sblk[0] + sblk[1] + sblk[2] + sblk[3]) * (1.0f / (float)BATCH);
        atomicAdd(out, bs);     // RELAXED device-scope HW f32 atomic (no fences)
    }
}

extern "C" void kernel_launch(void* const* d_in, const int* in_sizes, int n_in,
                              void* d_out, int out_size, void* d_ws, size_t ws_size,
                              hipStream_t stream) {
    const float* preds = (const float*)d_in[0];
    const float* Fs    = (const float*)d_in[1];
    float* out         = (float*)d_out;

    hipMemsetAsync(out, 0, sizeof(float), stream);   // d_out is poisoned each iter
    fft_loss_kernel<<<BATCH / 4, 256, 0, stream>>>(preds, Fs, out);
}

// Round 4
// 190.714 us; speedup vs baseline: 1.3434x; 1.3434x over previous
//
#include <hip/hip_runtime.h>
#include <cmath>

#define BATCH 32768

struct cplx { float x, y; };
__device__ __forceinline__ cplx cadd(cplx a, cplx b){ return {a.x+b.x, a.y+b.y}; }
__device__ __forceinline__ cplx csub(cplx a, cplx b){ return {a.x-b.x, a.y-b.y}; }
__device__ __forceinline__ cplx cmul(cplx a, cplx b){ return {a.x*b.x - a.y*b.y, a.x*b.y + a.y*b.x}; }
__device__ __forceinline__ cplx cmul_mi(cplx a){ return {a.y, -a.x}; }                 // a * (-i)
__device__ __forceinline__ cplx cmul_w81(cplx a){ const float c=0.70710678f; return {c*(a.x+a.y), c*(a.y-a.x)}; } // a*W8^1
__device__ __forceinline__ cplx cmul_w83(cplx a){ const float c=0.70710678f; return {c*(a.y-a.x), -c*(a.x+a.y)}; } // a*W8^3

// 8-point DFT, natural-order in/out: A_r = sum_m a_m * W8^{r m}
__device__ __forceinline__ void dft8(cplx a[8]) {
    cplx t0=cadd(a[0],a[4]), t4=csub(a[0],a[4]);
    cplx t1=cadd(a[1],a[5]), t5=csub(a[1],a[5]);
    cplx t2=cadd(a[2],a[6]), t6=csub(a[2],a[6]);
    cplx t3=cadd(a[3],a[7]), t7=csub(a[3],a[7]);
    cplx u0=cadd(t0,t2), u2=csub(t0,t2);
    cplx u1=cadd(t1,t3), u3=cmul_mi(csub(t1,t3));
    a[0]=cadd(u0,u1); a[4]=csub(u0,u1); a[2]=cadd(u2,u3); a[6]=csub(u2,u3);
    cplx v0=t4, v1=cmul_w81(t5), v2=cmul_mi(t6), v3=cmul_w83(t7);
    cplx w0=cadd(v0,v2), w2=csub(v0,v2);
    cplx w1=cadd(v1,v3), w3=cmul_mi(csub(v1,v3));
    a[1]=cadd(w0,w1); a[5]=csub(w0,w1); a[3]=cadd(w2,w3); a[7]=csub(w2,w3);
}

// Replicates JAX fp32 argmin(|freq - target|), first-occurrence tie-break.
__device__ __forceinline__ int nearest_bin(float fs, float target) {
    float x = target * 1024.0f / fs;
    int i0 = (int)floorf(x);
    int lo = max(0, i0 - 1), hi = min(512, i0 + 2);
    int bi = lo; float bd = 1e30f;
    for (int i = lo; i <= hi; ++i) {
        float fr = (fs * 0.5f) * ((float)i / 512.0f);
        float d = fabsf(fr - target);
        if (d < bd) { bd = d; bi = i; }
    }
    return bi;
}

// One wave (64 lanes) per row. 512-pt complex FFT of packed even/odd samples
// (radix 8x8x8). VALU-bound (round-3 PMC: 44us invariant VALU-issue time), so
// round-4 cuts instructions:
//  - total via Parseval: sum_k |X_k|^2 = 512*sum(x^2) + Re(Z0)^2 + Im(Z0)^2
//  - band [left,right) subset of [19,123] (fs in [25,35)) => only t=0,1 of the
//    rfft combine needed (partners from pruned stage-C outputs o6,o7)
//  - stage-B twiddle W_64^m0 = shfl(W_512^lane, 8*m0) replaces one sincos
//  - packed u64 wave argmax (float bits << 32 | ~k)
// Epilogue: partials + tiny reduce kernel. Round-1: per-block ACQ_REL atomics
// = 440us of L2 wb/inv. Round-3: even RELAXED same-line atomicAdd x8192 = +63us
// serialized at the coherent point. Do NOT fuse the final reduction.
__global__ __launch_bounds__(256) void fft_loss_kernel(
    const float* __restrict__ preds, const float* __restrict__ Fs,
    float* __restrict__ blockpartial)
{
    __shared__ float sre[4][576];   // per-wave: 8 rows x stride 72 (conflict-free)
    __shared__ float sim[4][576];
    __shared__ float sblk[4];

    const int tid  = threadIdx.x;
    const int wv   = tid >> 6;
    const int lane = tid & 63;
    const int row  = blockIdx.x * 4 + wv;

    float* re = sre[wv];
    float* im = sim[wv];

    const float fs = Fs[row];

    // z[n] = x[2n] + i*x[2n+1] == float2 view of the row.
    const float2* x2 = reinterpret_cast<const float2*>(preds) + (size_t)row * 512;

    // base twiddle W_512^lane (also feeds stage-B via shfl)
    cplx wA;
    { float sb, cb; __sincosf(-0.012271846f * (float)lane, &sb, &cb); wA = {cb, sb}; }

    // ---- Stage A: lane = n0; DFT8 over n1 (stride-64); accumulate sum(x^2) ----
    cplx z[8];
    float sq = 0.f;
#pragma unroll
    for (int n1 = 0; n1 < 8; ++n1) {
        float2 v = x2[n1 * 64 + lane];
        z[n1] = {v.x, v.y};
        sq = fmaf(v.x, v.x, fmaf(v.y, v.y, sq));
    }
    dft8(z);
    {   // twiddle W_512^{r*n0}, depth-3 power tree (verified: absmax 0.0)
        cplx w2 = cmul(wA, wA);
        cplx w3 = cmul(w2, wA);
        cplx w4 = cmul(w2, w2);
        cplx w5 = cmul(w4, wA);
        cplx w6 = cmul(w4, w2);
        cplx w7 = cmul(w4, w3);
        z[1]=cmul(z[1],wA); z[2]=cmul(z[2],w2); z[3]=cmul(z[3],w3); z[4]=cmul(z[4],w4);
        z[5]=cmul(z[5],w5); z[6]=cmul(z[6],w6); z[7]=cmul(z[7],w7);
    }
#pragma unroll
    for (int r = 0; r < 8; ++r) { re[r*72 + lane] = z[r].x; im[r*72 + lane] = z[r].y; }

    // ---- Stage B: lane = (r, m0); DFT8 over m1 ----
    const int rB = lane & 7, m0 = lane >> 3;
    cplx b[8];
#pragma unroll
    for (int m1 = 0; m1 < 8; ++m1) {
        int a = rB*72 + 8*m1 + m0;
        b[m1] = {re[a], im[a]};
    }
    dft8(b);
    {   // twiddle W_64^{s*m0}; W_64^{m0} = W_512^{8 m0} = shfl(wA, lane&56)
        cplx w1 = { __shfl(wA.x, lane & 56), __shfl(wA.y, lane & 56) };
        cplx w2 = cmul(w1, w1);
        cplx w3 = cmul(w2, w1);
        cplx w4 = cmul(w2, w2);
        cplx w5 = cmul(w4, w1);
        cplx w6 = cmul(w4, w2);
        cplx w7 = cmul(w4, w3);
        b[1]=cmul(b[1],w1); b[2]=cmul(b[2],w2); b[3]=cmul(b[3],w3); b[4]=cmul(b[4],w4);
        b[5]=cmul(b[5],w5); b[6]=cmul(b[6],w6); b[7]=cmul(b[7],w7);
    }
#pragma unroll
    for (int s = 0; s < 8; ++s) {   // XOR-swizzled 8x8 transpose (2-way banks both sides)
        int a = rB*72 + 8*m0 + ((s + m0) & 7);
        re[a] = b[s].x; im[a] = b[s].y;
    }

    // ---- Stage C: lane = (r, s); DFT8 over m0, pruned to outputs t in {0,1,6,7} ----
    const int sC = lane >> 3;
    cplx h[8];
#pragma unroll
    for (int m = 0; m < 8; ++m) {
        int a = rB*72 + 8*m + ((sC + m) & 7);
        h[m] = {re[a], im[a]};
    }
    cplx o0, o1, o6, o7;
    {
        cplx t0=cadd(h[0],h[4]), t4=csub(h[0],h[4]);
        cplx t1=cadd(h[1],h[5]), t5=csub(h[1],h[5]);
        cplx t2=cadd(h[2],h[6]), t6=csub(h[2],h[6]);
        cplx t3=cadd(h[3],h[7]), t7=csub(h[3],h[7]);
        cplx u0=cadd(t0,t2), u2=csub(t0,t2);
        cplx u1=cadd(t1,t3), u3=cmul_mi(csub(t1,t3));
        o0=cadd(u0,u1); o6=csub(u2,u3);
        cplx v0=t4, v1=cmul_w81(t5), v2=cmul_mi(t6), v3=cmul_w83(t7);
        cplx w0=cadd(v0,v2), w2=csub(v0,v2);
        cplx w1=cadd(v1,v3), w3=cmul_mi(csub(v1,v3));
        o1=cadd(w0,w1); o7=csub(w2,w3);
    }
    // Z[lane+64t]: t=0 -> o0, t=1 -> o1; partners Z[(512-k)&511] live in o6/o7.

    // ---- rfft combine for k in [0,128) only (band subset; total via Parseval) ----
    const int left  = nearest_bin(fs, (float)(40.0/60.0));  // in [19,28]
    const int right = nearest_bin(fs, 3.0f);                // in [87,123]

    float inb = 0.f;
    unsigned long long pk = 0ull;   // (psd_bits << 32) | ~k : max => argmax, min-idx ties
    float sk, ck;
    __sincosf(-0.0061359233f * (float)lane, &sk, &ck);      // -2pi/1024 * lane
    const cplx wb = {ck, sk};
    const int srcl = (64 - lane) & 63;
    const bool l0 = (lane == 0);

    // t = 0: k = lane; partner = o7 at lane (64-lane)&63 (lane0: o0 local)
    {
        cplx a = o0;
        float px = __shfl(o7.x, srcl), py = __shfl(o7.y, srcl);
        float bx = l0 ? o0.x : px;
        float by = l0 ? o0.y : py;
        float ex = 0.5f*(a.x + bx), ey = 0.5f*(a.y - by);
        float dx = a.x - bx,        dy = a.y + by;
        float ox = 0.5f*dy,         oy = -0.5f*dx;
        float Xr = ex + wb.x*ox - wb.y*oy;
        float Xi = ey + wb.x*oy + wb.y*ox;
        float v  = Xr*Xr + Xi*Xi;
        re[lane] = v;
        if (lane >= left) {         // k < right always (right >= 87 > 63)
            inb += v;
            unsigned long long cand =
                ((unsigned long long)__float_as_uint(v) << 32) | (unsigned)(~lane);
            if (cand > pk) pk = cand;
        }
    }
    // t = 1: k = 64+lane; partner = o6 at (64-lane)&63 (lane0: o7 local)
    {
        cplx a = o1;
        float px = __shfl(o6.x, srcl), py = __shfl(o6.y, srcl);
        float bx = l0 ? o7.x : px;
        float by = l0 ? o7.y : py;
        float ex = 0.5f*(a.x + bx), ey = 0.5f*(a.y - by);
        float dx = a.x - bx,        dy = a.y + by;
        float ox = 0.5f*dy,         oy = -0.5f*dx;
        cplx wk = cmul(wb, {0.92387953f, -0.38268343f});    // * W_16
        float Xr = ex + wk.x*ox - wk.y*oy;
        float Xi = ey + wk.x*oy + wk.y*ox;
        float v  = Xr*Xr + Xi*Xi;
        int k = 64 + lane;
        re[k] = v;
        if (k < right) {            // k >= left always (left <= 28 <= 64)
            inb += v;
            unsigned long long cand =
                ((unsigned long long)__float_as_uint(v) << 32) | (unsigned)(~k);
            if (cand > pk) pk = cand;
        }
    }

    // ---- wave reduce: sq, inb, packed argmax ----
#pragma unroll
    for (int off = 32; off > 0; off >>= 1) {
        sq  += __shfl_down(sq, off);
        inb += __shfl_down(inb, off);
        unsigned long long o = __shfl_down(pk, off);
        if (o > pk) pk = o;
    }
    if (lane == 0) {
        // Parseval: sum_{k=0..512}|X_k|^2 = 512*sum(x^2) + ReZ0^2 + ImZ0^2
        float total = fmaf(512.f, sq, o0.x*o0.x + o0.y*o0.y);
        int besti = (int)~((unsigned)(pk & 0xFFFFFFFFull));
        int delta = (int)rintf(0.1f / ((fs * 0.5f) / 513.0f));
        if (delta < 1) delta = 1;                       // delta in {3,4} for fs in [25,35)
        int lo = max(left, besti - delta), hi = min(right, besti + delta);
        float wsum = 0.f;
        for (int f = lo; f < hi; ++f) wsum += re[f];
        float band = (total - inb) / (1e-8f + total);
        float den  = inb + 1e-8f * (float)(right - left);
        sblk[wv] = band + (inb - wsum) / den;
    }
    __syncthreads();
    if (tid == 0) blockpartial[blockIdx.x] = sblk[0] + sblk[1] + sblk[2] + sblk[3];
}

__global__ __launch_bounds__(1024) void reduce_kernel(
    const float* __restrict__ bp, float* __restrict__ out)
{
    __shared__ float w[16];
    const int t = threadIdx.x;
    float acc = 0.f;
#pragma unroll
    for (int i = 0; i < 8; ++i) acc += bp[t + 1024*i];
    for (int off = 32; off > 0; off >>= 1) acc += __shfl_down(acc, off);
    const int lane = t & 63, wvi = t >> 6;
    if (lane == 0) w[wvi] = acc;
    __syncthreads();
    if (t == 0) {
        float s = 0.f;
        for (int i = 0; i < 16; ++i) s += w[i];
        out[0] = s * (1.0f / (float)BATCH);
    }
}

extern "C" void kernel_launch(void* const* d_in, const int* in_sizes, int n_in,
                              void* d_out, int out_size, void* d_ws, size_t ws_size,
                              hipStream_t stream) {
    const float* preds = (const float*)d_in[0];
    const float* Fs    = (const float*)d_in[1];
    float* bp          = (float*)d_ws;      // 8192 floats = 32 KB
    float* out         = (float*)d_out;

    fft_loss_kernel<<<BATCH / 4, 256, 0, stream>>>(preds, Fs, bp);
    reduce_kernel<<<1, 1024, 0, stream>>>(bp, out);
}

// Round 5
// 190.616 us; speedup vs baseline: 1.3441x; 1.0005x over previous
//
#include <hip/hip_runtime.h>
#include <cmath>

#define BATCH 32768

// Packed-complex: f2 maps to <2 x float>; gfx950 has v_pk_{add,mul,fma}_f32,
// so vector-typed complex arithmetic halves VALU instr count for adds and
// cuts cmul from 4 scalar ops to ~2-3 packed ops (round-5 change; the kernel
// is VALU-bound per round-3 PMC: 44us invariant VALU-issue time).
typedef float f2 __attribute__((ext_vector_type(2)));
__device__ __forceinline__ f2 mk(float x, float y){ f2 r; r.x = x; r.y = y; return r; }
__device__ __forceinline__ f2 cmul(f2 a, f2 b){
    // {ax,ax}*b + {-ay,ay}*{by,bx} = {ax bx - ay by, ax by + ay bx}
    return mk(-a.y, a.y) * mk(b.y, b.x) + mk(a.x, a.x) * b;   // pk_mul + pk_fma
}
__device__ __forceinline__ f2 cmul_mi(f2 a){ return mk(a.y, -a.x); }                 // a * (-i)
__device__ __forceinline__ f2 cmul_w81(f2 a){ const float c=0.70710678f; return mk(c,c) * mk(a.x+a.y, a.y-a.x); } // a*W8^1
__device__ __forceinline__ f2 cmul_w83(f2 a){ const float c=0.70710678f; return mk(c,-c) * mk(a.y-a.x, a.x+a.y); } // a*W8^3

// 8-point DFT, natural-order in/out: A_r = sum_m a_m * W8^{r m}
__device__ __forceinline__ void dft8(f2 a[8]) {
    f2 t0=a[0]+a[4], t4=a[0]-a[4];
    f2 t1=a[1]+a[5], t5=a[1]-a[5];
    f2 t2=a[2]+a[6], t6=a[2]-a[6];
    f2 t3=a[3]+a[7], t7=a[3]-a[7];
    f2 u0=t0+t2, u2=t0-t2;
    f2 u1=t1+t3, u3=cmul_mi(t1-t3);
    a[0]=u0+u1; a[4]=u0-u1; a[2]=u2+u3; a[6]=u2-u3;
    f2 v0=t4, v1=cmul_w81(t5), v2=cmul_mi(t6), v3=cmul_w83(t7);
    f2 w0=v0+v2, w2=v0-v2;
    f2 w1=v1+v3, w3=cmul_mi(v1-v3);
    a[1]=w0+w1; a[5]=w0-w1; a[3]=w2+w3; a[7]=w2-w3;
}

// Replicates JAX fp32 argmin(|freq - target|), first-occurrence tie-break.
__device__ __forceinline__ int nearest_bin(float fs, float target) {
    float x = target * 1024.0f / fs;
    int i0 = (int)floorf(x);
    int lo = max(0, i0 - 1), hi = min(512, i0 + 2);
    int bi = lo; float bd = 1e30f;
    for (int i = lo; i <= hi; ++i) {
        float fr = (fs * 0.5f) * ((float)i / 512.0f);
        float d = fabsf(fr - target);
        if (d < bd) { bd = d; bi = i; }
    }
    return bi;
}

// One wave (64 lanes) per row. 512-pt complex FFT of packed even/odd samples
// (radix 8x8x8). VALU-bound; instruction-count levers applied:
//  - packed v_pk_*_f32 complex arithmetic (this round)
//  - total via Parseval: sum_k |X_k|^2 = 512*sum(x^2) + Re(Z0)^2 + Im(Z0)^2
//  - band [left,right) subset of [19,123] (fs in [25,35)) => only t=0,1 of the
//    rfft combine needed (partners from pruned stage-C outputs o6,o7)
//  - stage-B twiddle W_64^m0 = shfl(W_512^lane, 8*m0) replaces one sincos
//  - packed u64 wave argmax (float bits << 32 | ~k)
// Epilogue: partials + tiny reduce kernel. Round-1: per-block ACQ_REL atomics
// = 440us of L2 wb/inv. Round-3: even RELAXED same-line atomicAdd x8192 = +63us
// serialized at the coherent point. Do NOT fuse the final reduction.
__global__ __launch_bounds__(256) void fft_loss_kernel(
    const float* __restrict__ preds, const float* __restrict__ Fs,
    float* __restrict__ blockpartial)
{
    __shared__ float sre[4][576];   // per-wave: 8 rows x stride 72 (conflict-free)
    __shared__ float sim[4][576];
    __shared__ float sblk[4];

    const int tid  = threadIdx.x;
    const int wv   = tid >> 6;
    const int lane = tid & 63;
    const int row  = blockIdx.x * 4 + wv;

    float* re = sre[wv];
    float* im = sim[wv];

    const float fs = Fs[row];

    // z[n] = x[2n] + i*x[2n+1] == float2 view of the row.
    const float2* x2 = reinterpret_cast<const float2*>(preds) + (size_t)row * 512;

    // base twiddle W_512^lane (also feeds stage-B via shfl)
    f2 wA;
    { float sb, cb; __sincosf(-0.012271846f * (float)lane, &sb, &cb); wA = mk(cb, sb); }

    // ---- Stage A: lane = n0; DFT8 over n1 (stride-64); accumulate sum(x^2) ----
    f2 z[8];
    float sq = 0.f;
#pragma unroll
    for (int n1 = 0; n1 < 8; ++n1) {
        float2 v = x2[n1 * 64 + lane];
        z[n1] = mk(v.x, v.y);
        sq = fmaf(v.x, v.x, fmaf(v.y, v.y, sq));
    }
    dft8(z);
    {   // twiddle W_512^{r*n0}, depth-3 power tree (verified: absmax 0.0)
        f2 w2 = cmul(wA, wA);
        f2 w3 = cmul(w2, wA);
        f2 w4 = cmul(w2, w2);
        f2 w5 = cmul(w4, wA);
        f2 w6 = cmul(w4, w2);
        f2 w7 = cmul(w4, w3);
        z[1]=cmul(z[1],wA); z[2]=cmul(z[2],w2); z[3]=cmul(z[3],w3); z[4]=cmul(z[4],w4);
        z[5]=cmul(z[5],w5); z[6]=cmul(z[6],w6); z[7]=cmul(z[7],w7);
    }
#pragma unroll
    for (int r = 0; r < 8; ++r) { re[r*72 + lane] = z[r].x; im[r*72 + lane] = z[r].y; }

    // ---- Stage B: lane = (r, m0); DFT8 over m1 ----
    const int rB = lane & 7, m0 = lane >> 3;
    f2 b[8];
#pragma unroll
    for (int m1 = 0; m1 < 8; ++m1) {
        int a = rB*72 + 8*m1 + m0;
        b[m1] = mk(re[a], im[a]);
    }
    dft8(b);
    {   // twiddle W_64^{s*m0}; W_64^{m0} = W_512^{8 m0} = shfl(wA, lane&56)
        f2 w1 = mk(__shfl(wA.x, lane & 56), __shfl(wA.y, lane & 56));
        f2 w2 = cmul(w1, w1);
        f2 w3 = cmul(w2, w1);
        f2 w4 = cmul(w2, w2);
        f2 w5 = cmul(w4, w1);
        f2 w6 = cmul(w4, w2);
        f2 w7 = cmul(w4, w3);
        b[1]=cmul(b[1],w1); b[2]=cmul(b[2],w2); b[3]=cmul(b[3],w3); b[4]=cmul(b[4],w4);
        b[5]=cmul(b[5],w5); b[6]=cmul(b[6],w6); b[7]=cmul(b[7],w7);
    }
#pragma unroll
    for (int s = 0; s < 8; ++s) {   // XOR-swizzled 8x8 transpose (2-way banks both sides)
        int a = rB*72 + 8*m0 + ((s + m0) & 7);
        re[a] = b[s].x; im[a] = b[s].y;
    }

    // ---- Stage C: lane = (r, s); DFT8 over m0, pruned to outputs t in {0,1,6,7} ----
    const int sC = lane >> 3;
    f2 h[8];
#pragma unroll
    for (int m = 0; m < 8; ++m) {
        int a = rB*72 + 8*m + ((sC + m) & 7);
        h[m] = mk(re[a], im[a]);
    }
    f2 o0, o1, o6, o7;
    {
        f2 t0=h[0]+h[4], t4=h[0]-h[4];
        f2 t1=h[1]+h[5], t5=h[1]-h[5];
        f2 t2=h[2]+h[6], t6=h[2]-h[6];
        f2 t3=h[3]+h[7], t7=h[3]-h[7];
        f2 u0=t0+t2, u2=t0-t2;
        f2 u1=t1+t3, u3=cmul_mi(t1-t3);
        o0=u0+u1; o6=u2-u3;
        f2 v0=t4, v1=cmul_w81(t5), v2=cmul_mi(t6), v3=cmul_w83(t7);
        f2 w0=v0+v2, w2=v0-v2;
        f2 w1=v1+v3, w3=cmul_mi(v1-v3);
        o1=w0+w1; o7=w2-w3;
    }
    // Z[lane+64t]: t=0 -> o0, t=1 -> o1; partners Z[(512-k)&511] live in o6/o7.

    // ---- rfft combine for k in [0,128) only (band subset; total via Parseval) ----
    const int left  = nearest_bin(fs, (float)(40.0/60.0));  // in [19,28]
    const int right = nearest_bin(fs, 3.0f);                // in [87,123]

    float inb = 0.f;
    unsigned long long pk = 0ull;   // (psd_bits << 32) | ~k : max => argmax, min-idx ties
    float sk, ck;
    __sincosf(-0.0061359233f * (float)lane, &sk, &ck);      // -2pi/1024 * lane
    const f2 wb = mk(ck, sk);
    const int srcl = (64 - lane) & 63;
    const bool l0 = (lane == 0);

    // t = 0: k = lane; partner = o7 at lane (64-lane)&63 (lane0: o0 local)
    {
        f2 a = o0;
        float px = __shfl(o7.x, srcl), py = __shfl(o7.y, srcl);
        float bx = l0 ? o0.x : px;
        float by = l0 ? o0.y : py;
        float ex = 0.5f*(a.x + bx), ey = 0.5f*(a.y - by);
        float dx = a.x - bx,        dy = a.y + by;
        float ox = 0.5f*dy,         oy = -0.5f*dx;
        float Xr = ex + wb.x*ox - wb.y*oy;
        float Xi = ey + wb.x*oy + wb.y*ox;
        float v  = Xr*Xr + Xi*Xi;
        re[lane] = v;
        if (lane >= left) {         // k < right always (right >= 87 > 63)
            inb += v;
            unsigned long long cand =
                ((unsigned long long)__float_as_uint(v) << 32) | (unsigned)(~lane);
            if (cand > pk) pk = cand;
        }
    }
    // t = 1: k = 64+lane; partner = o6 at (64-lane)&63 (lane0: o7 local)
    {
        f2 a = o1;
        float px = __shfl(o6.x, srcl), py = __shfl(o6.y, srcl);
        float bx = l0 ? o7.x : px;
        float by = l0 ? o7.y : py;
        float ex = 0.5f*(a.x + bx), ey = 0.5f*(a.y - by);
        float dx = a.x - bx,        dy = a.y + by;
        float ox = 0.5f*dy,         oy = -0.5f*dx;
        f2 wk = cmul(wb, mk(0.92387953f, -0.38268343f));    // * W_16
        float Xr = ex + wk.x*ox - wk.y*oy;
        float Xi = ey + wk.x*oy + wk.y*ox;
        float v  = Xr*Xr + Xi*Xi;
        int k = 64 + lane;
        re[k] = v;
        if (k < right) {            // k >= left always (left <= 28 <= 64)
            inb += v;
            unsigned long long cand =
                ((unsigned long long)__float_as_uint(v) << 32) | (unsigned)(~k);
            if (cand > pk) pk = cand;
        }
    }

    // ---- wave reduce: sq, inb, packed argmax ----
#pragma unroll
    for (int off = 32; off > 0; off >>= 1) {
        sq  += __shfl_down(sq, off);
        inb += __shfl_down(inb, off);
        unsigned long long o = __shfl_down(pk, off);
        if (o > pk) pk = o;
    }
    if (lane == 0) {
        // Parseval: sum_{k=0..512}|X_k|^2 = 512*sum(x^2) + ReZ0^2 + ImZ0^2
        float total = fmaf(512.f, sq, o0.x*o0.x + o0.y*o0.y);
        int besti = (int)~((unsigned)(pk & 0xFFFFFFFFull));
        int delta = (int)rintf(0.1f / ((fs * 0.5f) / 513.0f));
        if (delta < 1) delta = 1;                       // delta in {3,4} for fs in [25,35)
        int lo = max(left, besti - delta), hi = min(right, besti + delta);
        float wsum = 0.f;
        for (int f = lo; f < hi; ++f) wsum += re[f];
        float band = (total - inb) / (1e-8f + total);
        float den  = inb + 1e-8f * (float)(right - left);
        sblk[wv] = band + (inb - wsum) / den;
    }
    __syncthreads();
    if (tid == 0) blockpartial[blockIdx.x] = sblk[0] + sblk[1] + sblk[2] + sblk[3];
}

__global__ __launch_bounds__(1024) void reduce_kernel(
    const float* __restrict__ bp, float* __restrict__ out)
{
    __shared__ float w[16];
    const int t = threadIdx.x;
    float acc = 0.f;
#pragma unroll
    for (int i = 0; i < 8; ++i) acc += bp[t + 1024*i];
    for (int off = 32; off > 0; off >>= 1) acc += __shfl_down(acc, off);
    const int lane = t & 63, wvi = t >> 6;
    if (lane == 0) w[wvi] = acc;
    __syncthreads();
    if (t == 0) {
        float s = 0.f;
        for (int i = 0; i < 16; ++i) s += w[i];
        out[0] = s * (1.0f / (float)BATCH);
    }
}

extern "C" void kernel_launch(void* const* d_in, const int* in_sizes, int n_in,
                              void* d_out, int out_size, void* d_ws, size_t ws_size,
                              hipStream_t stream) {
    const float* preds = (const float*)d_in[0];
    const float* Fs    = (const float*)d_in[1];
    float* bp          = (float*)d_ws;      // 8192 floats = 32 KB
    float* out         = (float*)d_out;

    fft_loss_kernel<<<BATCH / 4, 256, 0, stream>>>(preds, Fs, bp);
    reduce_kernel<<<1, 1024, 0, stream>>>(bp, out);
}